// Round 6
// baseline (2642.014 us; speedup 1.0000x reference)
//
#include <hip/hip_runtime.h>

// CfC recurrence. Round 8:
//  - (R8) STRUCTURAL: producer/consumer wave specialization.
//    Waves 0-3 (producers): GEMM1 (h @ Wh, seeded with precomputed xz) +
//    lecun_tanh, each owning 64 of 256 z-cols. Waves 4-7 (consumers):
//    GEMM2 + combine, each owning 32 of 128 u. LDS reads drop 96 -> 48
//    ds_read_b128 per CU-step (redundancy scales with #waves holding each
//    role). Weight sets stay per-role-partial: producer 64 VGPR, consumer
//    192 VGPR-equiv (gfx950 unified VGPR/AGPR: persistent MFMA B-operands
//    can sit in AGPRs). Both role-loops execute exactly 2 barriers/iter;
//    cross-wave edges (z: producer->consumer, h: consumer->producer) each
//    covered by one barrier; consumer out-stores overlap the producer phase.
//  - (R7 carried) xz = x @ Wbb[x-part] + b_bb precomputed time-parallel into
//    d_ws (grid-256 kernel); fallback to the verified R5 kernel if no ws.

typedef __bf16 bf16;
typedef __bf16 bf16x8 __attribute__((ext_vector_type(8)));
typedef float  f32x4  __attribute__((ext_vector_type(4)));

#define BDIM 512

constexpr int B_  = 256;
constexpr int T_  = 1024;
constexpr int I_  = 64;
constexpr int U_  = 128;
constexpr int BB_ = 256;
constexpr int ROWS = 16;               // batch rows per block
constexpr int NBLK = B_ / ROWS;        // 16 blocks
constexpr int KO1  = (I_ + U_) / 8;    // 24 k-octets for A = [x | h] (fallback)

__device__ __forceinline__ float tanh_fast(float x) {
  float e = __builtin_amdgcn_exp2f(x * 2.8853900817779268f);
  return 1.0f - 2.0f * __builtin_amdgcn_rcpf(e + 1.0f);
}
__device__ __forceinline__ float sigmoid_fast(float x) {
  return __builtin_amdgcn_rcpf(1.0f + __builtin_amdgcn_exp2f(x * -1.4426950408889634f));
}

__device__ __forceinline__ void barrier_lds() {
  asm volatile("s_waitcnt lgkmcnt(0)" ::: "memory");
  __builtin_amdgcn_s_barrier();
}

// =====================  xz precompute (time-parallel)  ======================
// ws layout (float4 units): idx = ((bg*T + t)*16 + ct)*64 + l, where
// ct = col-tile (16 cols each) 0..15, holding the fp32 D-fragment of
// b_bb + x(t) @ Wbb[k=0..63] for lanes l (quad = l>>4 -> acc rows).
__global__ __launch_bounds__(512, 2)
void xz_precompute(const float* __restrict__ x,
                   const float* __restrict__ Wbb,
                   const float* __restrict__ bbb,
                   float4* __restrict__ ws)
{
  const int tid  = threadIdx.x;
  const int w    = tid >> 6;
  const int l    = tid & 63;
  const int quad = l >> 4;
  const int l16  = l & 15;
  const int bg   = blockIdx.x >> 4;          // 0..15
  const int t0   = (blockIdx.x & 15) * 64;   // 16 t-chunks of 64

  const int c1 = w * 32 + l16;               // ct = w*2 (+1 for +16)

  bf16x8 fx[2][2];
  #pragma unroll
  for (int ks = 0; ks < 2; ks++)
    #pragma unroll
    for (int nt = 0; nt < 2; nt++)
      #pragma unroll
      for (int j = 0; j < 8; j++)
        fx[ks][nt][j] = (bf16)Wbb[(ks * 32 + quad * 8 + j) * BB_ + c1 + nt * 16];

  const float bz0 = bbb[c1];
  const float bz1 = bbb[c1 + 16];

  const float* xs = x + ((size_t)(bg * ROWS + l16) * T_) * I_ + quad * 8;

  for (int t = t0; t < t0 + 64; ++t) {
    const float* xt = xs + (size_t)t * I_;
    float4 a0lo = *(const float4*)(xt);
    float4 a0hi = *(const float4*)(xt + 4);
    float4 a1lo = *(const float4*)(xt + 32);
    float4 a1hi = *(const float4*)(xt + 36);

    bf16x8 af[2];
    af[0][0]=(bf16)a0lo.x; af[0][1]=(bf16)a0lo.y; af[0][2]=(bf16)a0lo.z; af[0][3]=(bf16)a0lo.w;
    af[0][4]=(bf16)a0hi.x; af[0][5]=(bf16)a0hi.y; af[0][6]=(bf16)a0hi.z; af[0][7]=(bf16)a0hi.w;
    af[1][0]=(bf16)a1lo.x; af[1][1]=(bf16)a1lo.y; af[1][2]=(bf16)a1lo.z; af[1][3]=(bf16)a1lo.w;
    af[1][4]=(bf16)a1hi.x; af[1][5]=(bf16)a1hi.y; af[1][6]=(bf16)a1hi.z; af[1][7]=(bf16)a1hi.w;

    f32x4 az0 = { bz0, bz0, bz0, bz0 };
    f32x4 az1 = { bz1, bz1, bz1, bz1 };
    #pragma unroll
    for (int ks = 0; ks < 2; ks++) {
      az0 = __builtin_amdgcn_mfma_f32_16x16x32_bf16(af[ks], fx[ks][0], az0, 0, 0, 0);
      az1 = __builtin_amdgcn_mfma_f32_16x16x32_bf16(af[ks], fx[ks][1], az1, 0, 0, 0);
    }
    size_t base = ((size_t)(bg * T_ + t) * 16 + w * 2) * 64 + l;
    ws[base]      = *(const float4*)&az0;
    ws[base + 64] = *(const float4*)&az1;
  }
}

// ==========================  main recurrence (ws path)  =====================
__global__ __launch_bounds__(BDIM, 2)
void cfc_kernel_ws(const float* __restrict__ Wbb,
                   const float* __restrict__ Wff1, const float* __restrict__ bff1,
                   const float* __restrict__ Wff2, const float* __restrict__ bff2,
                   const float* __restrict__ Wta,  const float* __restrict__ bta,
                   const float* __restrict__ Wtb,  const float* __restrict__ btb,
                   const float4* __restrict__ ws,
                   float* __restrict__ out)
{
  // Fragment-linear LDS: elem(m, k) = ((k>>3)*ROWS + m)*8 + (k&7)
  __shared__ __align__(16) bf16 Abuf[16 * ROWS * 8];    // h, K=128, 4 KB
  __shared__ __align__(16) bf16 Zbuf[32 * ROWS * 8];    // z, K2=256, 8 KB

  const int tid  = threadIdx.x;
  const int w    = tid >> 6;       // wave 0..7
  const int l    = tid & 63;
  const int quad = l >> 4;
  const int l16  = l & 15;
  const int bg   = blockIdx.x;

  // zero Abuf (h0 = 0)
  for (int idx = tid; idx < 16 * ROWS * 8; idx += BDIM)
    Abuf[idx] = (bf16)0.0f;
  __syncthreads();

  if (w < 4) {
    // ================= producers: GEMM1 + lecun_tanh =================
    // cols c = w*64 + nt*16 + l16, nt = 0..3
    bf16x8 f1h[4][4];
    #pragma unroll
    for (int ks = 0; ks < 4; ks++)
      #pragma unroll
      for (int nt = 0; nt < 4; nt++)
        #pragma unroll
        for (int j = 0; j < 8; j++) {
          int k = 64 + ks * 32 + quad * 8 + j;
          f1h[ks][nt][j] = (bf16)Wbb[k * BB_ + w * 64 + nt * 16 + l16];
        }

    // xz: 4 consecutive records (ct = w*4 .. w*4+3), lane l reads float4 #l
    const float4* wsp = ws + ((size_t)bg * T_ * 16 + w * 4) * 64 + l;
    float4 xz[4];
    #pragma unroll
    for (int nt = 0; nt < 4; nt++) xz[nt] = wsp[nt * 64];

    for (int t = 0; t < T_; ++t) {
      // ---- GEMM1: az = xz(t) + h(t-1) @ Wh ----
      f32x4 az[4];
      #pragma unroll
      for (int nt = 0; nt < 4; nt++) az[nt] = *(const f32x4*)&xz[nt];
      #pragma unroll
      for (int ks = 0; ks < 4; ks++) {
        bf16x8 a = *(const bf16x8*)&Abuf[((ks * 4 + quad) * ROWS + l16) * 8];
        #pragma unroll
        for (int nt = 0; nt < 4; nt++)
          az[nt] = __builtin_amdgcn_mfma_f32_16x16x32_bf16(a, f1h[ks][nt], az[nt], 0, 0, 0);
      }
      // ---- lecun_tanh + z writes ----
      #pragma unroll
      for (int nt = 0; nt < 4; nt++) {
        const int c = w * 64 + nt * 16 + l16;
        #pragma unroll
        for (int i = 0; i < 4; i++) {
          int m = quad * 4 + i;
          float zv = 1.7159f * tanh_fast(0.666f * az[nt][i]);
          Zbuf[((c >> 3) * ROWS + m) * 8 + (c & 7)] = (bf16)zv;
        }
      }
      barrier_lds();   // barrier 1: z(t) visible to consumers

      // ---- idle window (consumers compute): prefetch xz(t+1) ----
      {
        const int tn = (t + 1 < T_) ? (t + 1) : (T_ - 1);
        const float4* p = wsp + (size_t)tn * (16 * 64);
        #pragma unroll
        for (int nt = 0; nt < 4; nt++) xz[nt] = p[nt * 64];
      }
      barrier_lds();   // barrier 2: h(t) visible for next GEMM1
    }
  } else {
    // ================= consumers: GEMM2 + combine =================
    const int w4 = w - 4;
    const int u0 = w4 * 32 + l16;    // units u0 + {0,16}

    bf16x8 g2[8][2][3];
    #pragma unroll
    for (int r = 0; r < 8; r++) {
      int ks = (2 * w4 + r) & 7;     // staggered z-chunk order per wave
      #pragma unroll
      for (int nt = 0; nt < 2; nt++)
        #pragma unroll
        for (int j = 0; j < 8; j++) {
          int k = ks * 32 + quad * 8 + j;
          int u = u0 + nt * 16;
          g2[r][nt][0][j] = (bf16)Wff1[k * U_ + u];
          g2[r][nt][1][j] = (bf16)Wff2[k * U_ + u];
          g2[r][nt][2][j] = (bf16)(Wta[k * U_ + u] + Wtb[k * U_ + u]);  // presum
        }
    }

    float bh[2][3];
    #pragma unroll
    for (int nt = 0; nt < 2; nt++) {
      bh[nt][0] = bff1[u0 + nt * 16];
      bh[nt][1] = bff2[u0 + nt * 16];
      bh[nt][2] = bta[u0 + nt * 16] + btb[u0 + nt * 16];
    }

    float* outp  = out + (size_t)(bg * ROWS) * T_ * U_ + u0;
    float* hlast = out + (size_t)B_ * T_ * U_ + (size_t)(bg * ROWS) * U_ + u0;
    const int h_oct = u0 >> 3;       // nt=1 adds 2 octets
    const int h_sub = u0 & 7;

    float hreg[2][4];

    for (int t = 0; t < T_; ++t) {
      // ---- store h(t-1) to global (overlaps producers' GEMM1 phase) ----
      if (t) {
        #pragma unroll
        for (int nt = 0; nt < 2; nt++)
          #pragma unroll
          for (int i = 0; i < 4; i++)
            outp[(size_t)(quad * 4 + i) * T_ * U_ + (size_t)(t - 1) * U_ + nt * 16] = hreg[nt][i];
      }
      barrier_lds();   // barrier 1: z(t) ready

      // ---- GEMM2: 6 independent chains of 8 ----
      f32x4 acc[2][3];
      #pragma unroll
      for (int nt = 0; nt < 2; nt++)
        #pragma unroll
        for (int o = 0; o < 3; o++)
          acc[nt][o] = f32x4{ bh[nt][o], bh[nt][o], bh[nt][o], bh[nt][o] };

      #pragma unroll
      for (int r = 0; r < 8; r++) {
        const int ks = (2 * w4 + r) & 7;
        bf16x8 zf = *(const bf16x8*)&Zbuf[((ks * 4 + quad) * ROWS + l16) * 8];
        #pragma unroll
        for (int nt = 0; nt < 2; nt++)
          #pragma unroll
          for (int o = 0; o < 3; o++)
            acc[nt][o] = __builtin_amdgcn_mfma_f32_16x16x32_bf16(zf, g2[r][nt][o], acc[nt][o], 0, 0, 0);
      }

      // ---- combine: h = ff1 + sigmoid(t)*(ff2 - ff1) ----
      #pragma unroll
      for (int nt = 0; nt < 2; nt++) {
        float ff1v[4], ff2v[4];
        #pragma unroll
        for (int i = 0; i < 4; i++) ff1v[i] = tanh_fast(acc[nt][0][i]);
        #pragma unroll
        for (int i = 0; i < 4; i++) ff2v[i] = tanh_fast(acc[nt][1][i]);
        #pragma unroll
        for (int i = 0; i < 4; i++) {
          int m = quad * 4 + i;
          float s = sigmoid_fast(acc[nt][2][i]);
          float h = ff1v[i] + s * (ff2v[i] - ff1v[i]);
          hreg[nt][i] = h;
          Abuf[((h_oct + nt * 2) * ROWS + m) * 8 + h_sub] = (bf16)h;
        }
      }
      barrier_lds();   // barrier 2: h(t) ready for producers
    }

    // tail: h(T-1) + h_last
    #pragma unroll
    for (int nt = 0; nt < 2; nt++)
      #pragma unroll
      for (int i = 0; i < 4; i++) {
        outp[(size_t)(quad * 4 + i) * T_ * U_ + (size_t)(T_ - 1) * U_ + nt * 16] = hreg[nt][i];
        hlast[(size_t)(quad * 4 + i) * U_ + nt * 16] = hreg[nt][i];
      }
  }
}

// =====================  fallback: verified R5 kernel  =======================
__global__ __launch_bounds__(BDIM, 2)
void cfc_kernel_fb(const float* __restrict__ x,
                   const float* __restrict__ Wbb,  const float* __restrict__ bbb,
                   const float* __restrict__ Wff1, const float* __restrict__ bff1,
                   const float* __restrict__ Wff2, const float* __restrict__ bff2,
                   const float* __restrict__ Wta,  const float* __restrict__ bta,
                   const float* __restrict__ Wtb,  const float* __restrict__ btb,
                   float* __restrict__ out)
{
  __shared__ __align__(16) bf16 Abuf[KO1 * ROWS * 8];
  __shared__ __align__(16) bf16 Zbuf[32  * ROWS * 8];

  const int tid  = threadIdx.x;
  const int w    = tid >> 6;
  const int l    = tid & 63;
  const int quad = l >> 4;
  const int l16  = l & 15;
  const int bg   = blockIdx.x;

  const int c1 = w * 32 + l16;
  const int u  = w * 16 + l16;

  bf16x8 f1[6][2];
  #pragma unroll
  for (int ks = 0; ks < 6; ks++)
    #pragma unroll
    for (int nt = 0; nt < 2; nt++)
      #pragma unroll
      for (int j = 0; j < 8; j++) {
        int k = ks * 32 + quad * 8 + j;
        f1[ks][nt][j] = (bf16)Wbb[k * BB_ + c1 + nt * 16];
      }

  bf16x8 g2[8][3];
  #pragma unroll
  for (int r = 0; r < 8; r++) {
    int ks = (w + r) & 7;
    #pragma unroll
    for (int j = 0; j < 8; j++) {
      int k = ks * 32 + quad * 8 + j;
      g2[r][0][j] = (bf16)Wff1[k * U_ + u];
      g2[r][1][j] = (bf16)Wff2[k * U_ + u];
      g2[r][2][j] = (bf16)(Wta[k * U_ + u] + Wtb[k * U_ + u]);
    }
  }

  const float bz0 = bbb[c1];
  const float bz1 = bbb[c1 + 16];
  const float bh0 = bff1[u];
  const float bh1 = bff2[u];
  const float bh2 = bta[u] + btb[u];

  for (int idx = tid; idx < (KO1 - 8) * ROWS * 8; idx += BDIM)
    Abuf[8 * ROWS * 8 + idx] = (bf16)0.0f;

  const int xm  = tid >> 5;
  const int xkk = tid & 31;
  const float* xsrc = x + ((size_t)(bg * ROWS + xm) * T_) * I_ + 2 * xkk;
  bf16* xdst = &Abuf[(((2 * xkk) >> 3) * ROWS + xm) * 8 + ((2 * xkk) & 7)];

  {
    float2 v = *(const float2*)xsrc;
    xdst[0] = (bf16)v.x;
    xdst[1] = (bf16)v.y;
  }
  __syncthreads();

  float* outp  = out + (size_t)(bg * ROWS) * T_ * U_ + u;
  float* hlast = out + (size_t)B_ * T_ * U_ + (size_t)(bg * ROWS) * U_ + u;

  const int h_oct = (64 + u) >> 3;
  const int h_sub = (64 + u) & 7;

  float hreg[4];
  float2 xv_cur = *(const float2*)(xsrc + I_);

  for (int t = 0; t < T_; ++t) {
    if (t) {
      #pragma unroll
      for (int i = 0; i < 4; i++)
        outp[(size_t)(quad * 4 + i) * T_ * U_ + (size_t)(t - 1) * U_] = hreg[i];
    }

    f32x4 az0 = { bz0, bz0, bz0, bz0 };
    f32x4 az1 = { bz1, bz1, bz1, bz1 };
    #pragma unroll
    for (int ks = 0; ks < 6; ks++) {
      bf16x8 a = *(const bf16x8*)&Abuf[((ks * 4 + quad) * ROWS + l16) * 8];
      az0 = __builtin_amdgcn_mfma_f32_16x16x32_bf16(a, f1[ks][0], az0, 0, 0, 0);
      az1 = __builtin_amdgcn_mfma_f32_16x16x32_bf16(a, f1[ks][1], az1, 0, 0, 0);
    }
    #pragma unroll
    for (int i = 0; i < 4; i++) {
      int m = quad * 4 + i;
      float z0 = 1.7159f * tanh_fast(0.666f * az0[i]);
      float z1 = 1.7159f * tanh_fast(0.666f * az1[i]);
      int c0 = c1, cB = c1 + 16;
      Zbuf[((c0 >> 3) * ROWS + m) * 8 + (c0 & 7)] = (bf16)z0;
      Zbuf[((cB >> 3) * ROWS + m) * 8 + (cB & 7)] = (bf16)z1;
    }

    f32x4 a0 = { bh0, bh0, bh0, bh0 };
    f32x4 a1 = { bh1, bh1, bh1, bh1 };
    f32x4 a2 = { bh2, bh2, bh2, bh2 };
    {
      bf16x8 zf0 = *(const bf16x8*)&Zbuf[((w * 4 + quad) * ROWS + l16) * 8];
      a0 = __builtin_amdgcn_mfma_f32_16x16x32_bf16(zf0, g2[0][0], a0, 0, 0, 0);
      a1 = __builtin_amdgcn_mfma_f32_16x16x32_bf16(zf0, g2[0][1], a1, 0, 0, 0);
      a2 = __builtin_amdgcn_mfma_f32_16x16x32_bf16(zf0, g2[0][2], a2, 0, 0, 0);
    }
    barrier_lds();

    bf16x8 zf[7];
    #pragma unroll
    for (int r = 1; r < 8; r++) {
      const int ks = (w + r) & 7;
      zf[r - 1] = *(const bf16x8*)&Zbuf[((ks * 4 + quad) * ROWS + l16) * 8];
    }

    xdst[0] = (bf16)xv_cur.x;
    xdst[1] = (bf16)xv_cur.y;
    {
      const int tn = (t + 2 < T_) ? (t + 2) : (T_ - 1);
      xv_cur = *(const float2*)(xsrc + (size_t)tn * I_);
    }

    #pragma unroll
    for (int r = 1; r < 8; r++) {
      a0 = __builtin_amdgcn_mfma_f32_16x16x32_bf16(zf[r - 1], g2[r][0], a0, 0, 0, 0);
      a1 = __builtin_amdgcn_mfma_f32_16x16x32_bf16(zf[r - 1], g2[r][1], a1, 0, 0, 0);
    }
    #pragma unroll
    for (int r = 1; r < 8; r++)
      a2 = __builtin_amdgcn_mfma_f32_16x16x32_bf16(zf[r - 1], g2[r][2], a2, 0, 0, 0);

    float ff1v[4], ff2v[4];
    #pragma unroll
    for (int i = 0; i < 4; i++) ff1v[i] = tanh_fast(a0[i]);
    #pragma unroll
    for (int i = 0; i < 4; i++) ff2v[i] = tanh_fast(a1[i]);

    #pragma unroll
    for (int i = 0; i < 4; i++) {
      int m = quad * 4 + i;
      float s = sigmoid_fast(a2[i]);
      float h = ff1v[i] + s * (ff2v[i] - ff1v[i]);
      hreg[i] = h;
      Abuf[(h_oct * ROWS + m) * 8 + h_sub] = (bf16)h;
    }

    barrier_lds();
  }

  #pragma unroll
  for (int i = 0; i < 4; i++) {
    outp[(size_t)(quad * 4 + i) * T_ * U_ + (size_t)(T_ - 1) * U_] = hreg[i];
    hlast[(size_t)(quad * 4 + i) * U_] = hreg[i];
  }
}

extern "C" void kernel_launch(void* const* d_in, const int* in_sizes, int n_in,
                              void* d_out, int out_size, void* d_ws, size_t ws_size,
                              hipStream_t stream) {
  const float* x    = (const float*)d_in[0];
  const float* Wbb  = (const float*)d_in[1];
  const float* bbb  = (const float*)d_in[2];
  const float* Wff1 = (const float*)d_in[3];
  const float* bff1 = (const float*)d_in[4];
  const float* Wff2 = (const float*)d_in[5];
  const float* bff2 = (const float*)d_in[6];
  const float* Wta  = (const float*)d_in[7];
  const float* bta  = (const float*)d_in[8];
  const float* Wtb  = (const float*)d_in[9];
  const float* btb  = (const float*)d_in[10];
  float* out = (float*)d_out;
  (void)in_sizes; (void)n_in; (void)out_size;

  const size_t need = (size_t)NBLK * T_ * 16 * 64 * sizeof(float4);  // 256 MiB

  if (d_ws != nullptr && ws_size >= need) {
    float4* ws = (float4*)d_ws;
    hipLaunchKernelGGL(xz_precompute, dim3(256), dim3(512), 0, stream,
                       x, Wbb, bbb, ws);
    hipLaunchKernelGGL(cfc_kernel_ws, dim3(NBLK), dim3(BDIM), 0, stream,
                       Wbb, Wff1, bff1, Wff2, bff2, Wta, bta, Wtb, btb,
                       (const float4*)ws, out);
  } else {
    hipLaunchKernelGGL(cfc_kernel_fb, dim3(NBLK), dim3(BDIM), 0, stream,
                       x, Wbb, bbb, Wff1, bff1, Wff2, bff2, Wta, bta, Wtb, btb, out);
  }
}